// Round 3
// baseline (3078.360 us; speedup 1.0000x reference)
//
#include <hip/hip_runtime.h>
#include <hip/hip_bf16.h>
#include <cstdint>

// LGnet_mem, chunked-timeline + runtime dtype detection.
//   kprobe  : detect input dtype (fp32 vs bf16) from Wz bit patterns -> flag in ws
//   kconv   : canonicalize all 16 weight arrays to fp32 in ws (dual-path loads)
//   k0a/k0b : fold weights  U = Wg1·(Wq3·Wfc)+Wg2, Wfold = Wg1·Wq12, biases; swizzle
//   per chunk of TC=25 steps:
//     k1c : z,zp elementwise  -> ZZc [tt*256+b][256] f16   (dual-path inp/xmean loads)
//     k2c : Gc = ZZc @ Wfold.T + bfold   [tt][1024][256] f16
//     k3c : serial scan (16 WGs x 16 batch rows), pre = Gc + h@U.T, gates, c/h,
//           fused out = h@Wfc.T + bfc -> d_out (dtype per flag)

#define TC_ 25
#define NC_ 8

typedef _Float16 half8  __attribute__((ext_vector_type(8)));
typedef _Float16 half4v __attribute__((ext_vector_type(4)));
typedef float    floatx4 __attribute__((ext_vector_type(4)));

// ws layout (byte offsets); total 0x12C0000 = 19.7 MB
#define OFF_FLAG   0x000000ULL
#define OFF_A32    0x001000ULL    // 64x256 f32
#define OFF_BQ2    0x011000ULL    // 64 f32
#define OFF_BFOLD  0x011400ULL    // 1024 f32
#define OFF_CAN    0x012400ULL    // 419264 f32 canonical weights
#define OFF_USW    0x1B0000ULL    // 1024x256 f16 swizzled
#define OFF_WFSW   0x230000ULL    // 1024x256 f16 swizzled
#define OFF_WFCSW  0x2B0000ULL    // 128x256 f16 swizzled
#define OFF_HST    0x2C0000ULL    // 256x256 f16
#define OFF_CST    0x2E0000ULL    // 256x256 f32
#define OFF_ZZC    0x320000ULL    // [TC*256][256] f16
#define OFF_GC     0x640000ULL    // [TC][1024][256] f16

// canonical weight element offsets (fp32 units)
#define CW_WZ   0
#define CW_BZ   16384
#define CW_WZP  16512
#define CW_BZP  32896
#define CW_WQ   33024
#define CW_BQ   57600
#define CW_WI   57664
#define CW_BI   139584
#define CW_WF   139840
#define CW_BF   221760
#define CW_WO   222016
#define CW_BO   303936
#define CW_WC   304192
#define CW_BC   386112
#define CW_WFC  386368
#define CW_BFC  419136
#define CW_TOT  419264

__device__ __forceinline__ float sigmoid_(float x) {
    return 1.0f / (1.0f + __expf(-x));
}
__device__ __forceinline__ float tanh_(float x) {
    float e = __expf(2.0f * x);
    return 1.0f - 2.0f / (e + 1.0f);
}
__device__ __forceinline__ float ldin(const void* p, size_t i, bool f32) {
    return f32 ? ((const float*)p)[i]
               : __bfloat162float(((const __hip_bfloat16*)p)[i]);
}

// B-operand fragment swizzle for mfma_f32_16x16x32_f16:
// W[n][k] -> ((nt*8+kt)*64 + q*16 + (n&15))*8 + j   with k = kt*32+q*8+j
__device__ __forceinline__ int swz(int row, int k) {
    int nt = row >> 4, lr2 = row & 15;
    int kt = k >> 5, qq = (k >> 3) & 3, j = k & 7;
    return (((nt * 8 + kt) * 64) + (qq * 16 + lr2)) * 8 + j;
}

// --- dtype probe: Wz is uniform(+-0.088). Read as bf16 at even indices:
// bf16 data -> values <= 0.09 ; fp32 data -> low mantissa halves, max >> 1e4.
__global__ void kprobe(const void* __restrict__ wzraw, float* __restrict__ flag)
{
    __shared__ float red[256];
    int tid = threadIdx.x;
    const __hip_bfloat16* p = (const __hip_bfloat16*)wzraw;
    float mx = 0.f;
    for (int i = tid; i < 8192; i += 256) {
        float v = fabsf(__bfloat162float(p[2 * i]));
        if (!(v < 1e30f)) v = 1e30f;            // clamp inf/nan
        mx = fmaxf(mx, v);
    }
    red[tid] = mx;
    __syncthreads();
    for (int s = 128; s > 0; s >>= 1) {
        if (tid < s) red[tid] = fmaxf(red[tid], red[tid + s]);
        __syncthreads();
    }
    if (tid == 0) flag[0] = (red[0] > 1e4f) ? 1.0f : 0.0f;
}

// --- canonicalize all weights to fp32
__global__ void kconv(const float* __restrict__ flag,
                      const void* Wz,  const void* bz,  const void* Wzp, const void* bzp,
                      const void* Wq,  const void* bq,
                      const void* Wi,  const void* bi,  const void* Wf,  const void* bf,
                      const void* Wo,  const void* bo,  const void* Wc,  const void* bc,
                      const void* Wfc, const void* bfc,
                      float* __restrict__ can)
{
    const int sizes[16] = {16384,128,16384,128,24576,64,81920,256,81920,256,
                           81920,256,81920,256,32768,128};
    const int offs[16]  = {CW_WZ,CW_BZ,CW_WZP,CW_BZP,CW_WQ,CW_BQ,CW_WI,CW_BI,
                           CW_WF,CW_BF,CW_WO,CW_BO,CW_WC,CW_BC,CW_WFC,CW_BFC};
    const void* srcs[16] = {Wz,bz,Wzp,bzp,Wq,bq,Wi,bi,Wf,bf,Wo,bo,Wc,bc,Wfc,bfc};
    int aid = blockIdx.y;
    int i = blockIdx.x * 256 + threadIdx.x;
    if (i >= sizes[aid]) return;
    bool f32 = flag[0] > 0.5f;
    can[offs[aid] + i] = ldin(srcs[aid], i, f32);
}

__global__ void k0a(const float* __restrict__ can,
                    float* __restrict__ A32, float* __restrict__ bq2)
{
    int idx = blockIdx.x * 256 + threadIdx.x;
    if (idx < 16384) {                       // A = Wq3 @ Wfc   [64,256]
        int m = idx >> 8, k = idx & 255;
        float s = 0.f;
        for (int p = 0; p < 128; ++p)
            s += can[CW_WQ + m * 384 + 256 + p] * can[CW_WFC + p * 256 + k];
        A32[idx] = s;
    } else if (idx < 16448) {                // bq2 = bq + Wq3 @ bfc
        int m = idx - 16384;
        float s = can[CW_BQ + m];
        for (int p = 0; p < 128; ++p)
            s += can[CW_WQ + m * 384 + 256 + p] * can[CW_BFC + p];
        bq2[m] = s;
    }
}

__global__ void k0b(const float* __restrict__ can,
                    const float* __restrict__ A32, const float* __restrict__ bq2,
                    _Float16* __restrict__ U_sw, _Float16* __restrict__ Wf_sw,
                    _Float16* __restrict__ Wfc_sw, float* __restrict__ bfold)
{
    int blk = blockIdx.x, k = threadIdx.x;
    if (blk < 1024) {
        int g = blk >> 8, j = blk & 255;
        const float* Wg = can + (g == 0 ? CW_WI : g == 1 ? CW_WF : g == 2 ? CW_WO : CW_WC);
        const float* bg = can + (g == 0 ? CW_BI : g == 1 ? CW_BF : g == 2 ? CW_BO : CW_BC);
        float su = 0.f, sw = 0.f;
        for (int m = 0; m < 64; ++m) {
            float wgm = Wg[j * 320 + m];
            su += wgm * A32[m * 256 + k];            // Wg1 @ (Wq3@Wfc)
            sw += wgm * can[CW_WQ + m * 384 + k];    // Wg1 @ Wq12
        }
        su += Wg[j * 320 + 64 + k];                  // + Wg2
        U_sw[swz(blk, k)]  = (_Float16)su;
        Wf_sw[swz(blk, k)] = (_Float16)sw;
        if (k == 0) {
            float sb = bg[j];
            for (int m = 0; m < 64; ++m)
                sb += Wg[j * 320 + m] * bq2[m];
            bfold[blk] = sb;
        }
    } else {                                 // swizzle Wfc for fused out-GEMM
        int n = blk - 1024;
        Wfc_sw[swz(n, k)] = (_Float16)can[CW_WFC + n * 256 + k];
    }
}

__global__ void k1c(const float* __restrict__ flag,
                    const void* __restrict__ inp, const void* __restrict__ xmean,
                    const float* __restrict__ can,
                    _Float16* __restrict__ ZZc, int t0)
{
    int idx = blockIdx.x * 256 + threadIdx.x;   // over TC*256*128
    int j    = idx & 127;
    int rloc = idx >> 7;                        // tt*256 + b
    int b    = rloc & 255;
    int tt   = rloc >> 8;
    int t    = t0 + tt;
    bool f32 = flag[0] > 0.5f;
    size_t base = ((size_t)b * 6 * 200 + t) * 128 + j;
    const int CS = 200 * 128;
    float x   = ldin(inp, base, f32);
    float xl  = ldin(inp, base + CS, f32);
    float mk  = ldin(inp, base + 2 * CS, f32);
    float d   = ldin(inp, base + 3 * CS, f32);
    float xlb = ldin(inp, base + 4 * CS, f32);
    float db  = ldin(inp, base + 5 * CS, f32);
    float xm  = ldin(xmean, ((size_t)b * 200 + t) * 128 + j, f32);
    float dz  = __expf(-fmaxf(d  * can[CW_WZ  + j * 129] + can[CW_BZ  + j], 0.f));
    float dzp = __expf(-fmaxf(db * can[CW_WZP + j * 129] + can[CW_BZP + j], 0.f));
    float z  = mk * x + (1.f - mk) * (dz  * xl  + (1.f - dz)  * xm);
    float zp = mk * x + (1.f - mk) * (dzp * xlb + (1.f - dzp) * xm);
    ZZc[(size_t)rloc * 256 + j]       = (_Float16)z;
    ZZc[(size_t)rloc * 256 + 128 + j] = (_Float16)zp;
}

// Gc[tt][n][b] = ZZc[tt*256+b][:] . Wfold[n][:] + bfold[n]
__global__ __launch_bounds__(512, 2)
void k2c(const _Float16* __restrict__ ZZc, const _Float16* __restrict__ Wf_sw,
         const float* __restrict__ bfold, _Float16* __restrict__ Gc)
{
    const int mt = blockIdx.x;       // TC*4 tiles of 64 rows
    const int nc = blockIdx.y;       // 4 chunks of 256 gate-cols
    const int tid = threadIdx.x;
    const int w = tid >> 6, L = tid & 63, q = L >> 4, lr = L & 15;
    const int row0 = mt * 64 + (w & 3) * 16;
    const int nt0 = nc * 16 + (w >> 2) * 8;

    const half8* __restrict__ Wb = (const half8*)Wf_sw;
    floatx4 acc[8];
#pragma unroll
    for (int i = 0; i < 8; ++i) {
        float bv = bfold[(nt0 + i) * 16 + lr];
        acc[i] = (floatx4){bv, bv, bv, bv};
    }
#pragma unroll
    for (int kt = 0; kt < 8; ++kt) {
        half8 a = *(const half8*)(ZZc + (size_t)(row0 + lr) * 256 + kt * 32 + q * 8);
#pragma unroll
        for (int i = 0; i < 8; ++i) {
            half8 b = Wb[(((nt0 + i) * 8) + kt) * 64 + L];
            acc[i] = __builtin_amdgcn_mfma_f32_16x16x32_f16(a, b, acc[i], 0, 0, 0);
        }
    }
    const int tt = row0 >> 8;
    const int b0 = (row0 & 255) + q * 4;
#pragma unroll
    for (int i = 0; i < 8; ++i) {
        int n = (nt0 + i) * 16 + lr;
        half4v pk;
#pragma unroll
        for (int r = 0; r < 4; ++r) pk[r] = (_Float16)acc[i][r];
        *(half4v*)(Gc + (((size_t)tt * 1024 + n) << 8) + b0) = pk;
    }
}

// Serial scan chunk: 16 WGs x 16 batch rows, 8 waves.
__global__ __launch_bounds__(512)
void k3c(int t0, const float* __restrict__ flag,
         const _Float16* __restrict__ U_sw, const _Float16* __restrict__ Wfc_sw,
         const float* __restrict__ can, const _Float16* __restrict__ Gc,
         _Float16* __restrict__ Hst, float* __restrict__ Cst,
         void* __restrict__ outv)
{
    const int wg = blockIdx.x;           // 16
    const int tid = threadIdx.x;
    const int w = tid >> 6, L = tid & 63;
    const int q = L >> 4, lr = L & 15;
    const bool f32m = flag[0] > 0.5f;

    __shared__ _Float16 h16[16 * 264];    // [row][k], +8 pad
    __shared__ _Float16 g16[16 * 1032];   // [row][n], +8 pad

    for (int i = tid; i < 16 * 256; i += 512) {
        int m = i >> 8, k = i & 255;
        h16[m * 264 + k] = Hst[(size_t)(wg * 16 + m) * 256 + k];
    }

    const half8* __restrict__ Ub = (const half8*)U_sw;
    const half8* __restrict__ Wb = (const half8*)Wfc_sw;
    half8 bp[4][8];                      // persistent U tiles nt = w*8..w*8+3
#pragma unroll
    for (int i = 0; i < 4; ++i)
#pragma unroll
        for (int kt = 0; kt < 8; ++kt)
            bp[i][kt] = Ub[(((w * 8 + i) * 8) + kt) * 64 + L];

    const int m_ew = tid >> 5;
    const int j0   = (tid & 31) * 8;
    float creg[8];
#pragma unroll
    for (int jj = 0; jj < 8; ++jj)
        creg[jj] = Cst[(size_t)(wg * 16 + m_ew) * 256 + j0 + jj];

    const float bfc_l = can[CW_BFC + w * 16 + lr];
    const bool do_tanh = (w >= 6);       // waves 6,7: candidate gate (n>=768)
    __syncthreads();

    for (int tt = 0; tt < TC_; ++tt) {
        const int t = t0 + tt;
        half4v gpre[8];
#pragma unroll
        for (int i = 0; i < 8; ++i) {
            int n = (w * 8 + i) * 16 + lr;
            gpre[i] = *(const half4v*)(Gc + (((size_t)tt * 1024 + n) << 8) + wg * 16 + q * 4);
        }
        floatx4 acc[8];
#pragma unroll
        for (int i = 0; i < 8; ++i) acc[i] = (floatx4){0.f, 0.f, 0.f, 0.f};

        half8 bs[4], bsn[4];
#pragma unroll
        for (int i = 0; i < 4; ++i)
            bs[i] = Ub[(((w * 8 + 4 + i) * 8) + 0) * 64 + L];

#pragma unroll
        for (int kt = 0; kt < 8; ++kt) {
            half8 a = *(const half8*)(&h16[lr * 264 + kt * 32 + q * 8]);
            if (kt < 7) {
#pragma unroll
                for (int i = 0; i < 4; ++i)
                    bsn[i] = Ub[(((w * 8 + 4 + i) * 8) + kt + 1) * 64 + L];
            }
#pragma unroll
            for (int i = 0; i < 4; ++i)
                acc[i] = __builtin_amdgcn_mfma_f32_16x16x32_f16(a, bp[i][kt], acc[i], 0, 0, 0);
#pragma unroll
            for (int i = 0; i < 4; ++i)
                acc[4 + i] = __builtin_amdgcn_mfma_f32_16x16x32_f16(a, bs[i], acc[4 + i], 0, 0, 0);
#pragma unroll
            for (int i = 0; i < 4; ++i) bs[i] = bsn[i];
        }

#pragma unroll
        for (int i = 0; i < 8; ++i) {
            int n = (w * 8 + i) * 16 + lr;
#pragma unroll
            for (int r = 0; r < 4; ++r) {
                float x = acc[i][r] + (float)gpre[i][r];
                x = do_tanh ? tanh_(x) : sigmoid_(x);
                g16[(q * 4 + r) * 1032 + n] = (_Float16)x;
            }
        }
        __syncthreads();

        half8 iv = *(const half8*)(&g16[m_ew * 1032 + 0   + j0]);
        half8 fv = *(const half8*)(&g16[m_ew * 1032 + 256 + j0]);
        half8 ov = *(const half8*)(&g16[m_ew * 1032 + 512 + j0]);
        half8 cv = *(const half8*)(&g16[m_ew * 1032 + 768 + j0]);
        half8 hv;
#pragma unroll
        for (int jj = 0; jj < 8; ++jj) {
            float c = (float)fv[jj] * creg[jj] + (float)iv[jj] * (float)cv[jj];
            creg[jj] = c;
            hv[jj] = (_Float16)((float)ov[jj] * tanh_(c));
        }
        *(half8*)(&h16[m_ew * 264 + j0]) = hv;
        __syncthreads();

        // fused out-GEMM: wave w owns out cols [w*16, w*16+16)
        floatx4 ao = (floatx4){bfc_l, bfc_l, bfc_l, bfc_l};
#pragma unroll
        for (int kt = 0; kt < 8; ++kt) {
            half8 a = *(const half8*)(&h16[lr * 264 + kt * 32 + q * 8]);
            half8 b = Wb[((w * 8) + kt) * 64 + L];
            ao = __builtin_amdgcn_mfma_f32_16x16x32_f16(a, b, ao, 0, 0, 0);
        }
        {
            int n = w * 16 + lr;
            if (f32m) {
                float* o32 = (float*)outv;
#pragma unroll
                for (int r = 0; r < 4; ++r) {
                    int b = wg * 16 + q * 4 + r;
                    o32[((size_t)b * 200 + t) * 128 + n] = ao[r];
                }
            } else {
                __hip_bfloat16* o16 = (__hip_bfloat16*)outv;
#pragma unroll
                for (int r = 0; r < 4; ++r) {
                    int b = wg * 16 + q * 4 + r;
                    o16[((size_t)b * 200 + t) * 128 + n] = __float2bfloat16(ao[r]);
                }
            }
        }
        __syncthreads();
    }

    for (int i = tid; i < 16 * 256; i += 512) {
        int m = i >> 8, k = i & 255;
        Hst[(size_t)(wg * 16 + m) * 256 + k] = h16[m * 264 + k];
    }
#pragma unroll
    for (int jj = 0; jj < 8; ++jj)
        Cst[(size_t)(wg * 16 + m_ew) * 256 + j0 + jj] = creg[jj];
}

extern "C" void kernel_launch(void* const* d_in, const int* in_sizes, int n_in,
                              void* d_out, int out_size, void* d_ws, size_t ws_size,
                              hipStream_t stream)
{
    char* ws = (char*)d_ws;
    float*     flag   = (float*)(ws + OFF_FLAG);
    float*     A32    = (float*)(ws + OFF_A32);
    float*     bq2    = (float*)(ws + OFF_BQ2);
    float*     bfold  = (float*)(ws + OFF_BFOLD);
    float*     can    = (float*)(ws + OFF_CAN);
    _Float16*  U_sw   = (_Float16*)(ws + OFF_USW);
    _Float16*  Wf_sw  = (_Float16*)(ws + OFF_WFSW);
    _Float16*  Wfc_sw = (_Float16*)(ws + OFF_WFCSW);
    _Float16*  Hst    = (_Float16*)(ws + OFF_HST);
    float*     Cst    = (float*)(ws + OFF_CST);
    _Float16*  ZZc    = (_Float16*)(ws + OFF_ZZC);
    _Float16*  Gc     = (_Float16*)(ws + OFF_GC);

    kprobe<<<1, 256, 0, stream>>>(d_in[2], flag);
    kconv<<<dim3(320, 16), 256, 0, stream>>>(flag,
        d_in[2], d_in[3], d_in[4], d_in[5], d_in[6], d_in[7],
        d_in[8], d_in[9], d_in[10], d_in[11], d_in[12], d_in[13],
        d_in[14], d_in[15], d_in[16], d_in[17], can);
    k0a<<<65, 256, 0, stream>>>(can, A32, bq2);
    k0b<<<1152, 256, 0, stream>>>(can, A32, bq2, U_sw, Wf_sw, Wfc_sw, bfold);
    hipMemsetAsync(ws + OFF_HST, 0, 0x60000, stream);   // zero h,c state

    for (int c = 0; c < NC_; ++c) {
        int t0 = c * TC_;
        k1c<<<TC_ * 128, 256, 0, stream>>>(flag, d_in[0], d_in[1], can, ZZc, t0);
        k2c<<<dim3(TC_ * 4, 4), 512, 0, stream>>>(ZZc, Wf_sw, bfold, Gc);
        k3c<<<16, 512, 0, stream>>>(t0, flag, U_sw, Wfc_sw, can, Gc, Hst, Cst, d_out);
    }
}